// Round 1
// baseline (857.727 us; speedup 1.0000x reference)
//
#include <hip/hip_runtime.h>

// Invert4_10: elementwise 16-step spiking scan over x (8,4096,4096) fp32.
// Memory-bound streaming kernel. Spike simplification:
//   v_scaled = (v - T)/( |v|+1 ) > 0  <=>  v > T   (denominator always >= 1)
// so no division is needed.

__global__ __launch_bounds__(256) void invert4_kernel(
    const float* __restrict__ x,
    const float* __restrict__ h,
    const float* __restrict__ d,
    const float* __restrict__ T,
    float* __restrict__ out,
    int n4)
{
    int idx = blockIdx.x * blockDim.x + threadIdx.x;
    if (idx >= n4) return;

    // Broadcast constant loads (same address across wave -> 1 txn, L1-hot).
    float hh[16], dd[16], TT[16];
#pragma unroll
    for (int t = 0; t < 16; ++t) {
        hh[t] = h[t];
        dd[t] = d[t];
        TT[t] = T[t];
    }

    const float4* __restrict__ x4 = (const float4*)x;
    float4 xv = x4[idx];

    float xin[4] = {xv.x, xv.y, xv.z, xv.w};
    float r[4];

#pragma unroll
    for (int i = 0; i < 4; ++i) {
        const float xi = xin[i];
        float v = fabsf(xi);
        float z = 0.0f;
        float o = 0.0f;
#pragma unroll
        for (int t = 0; t < 16; ++t) {
            v -= z * hh[t];
            z = (v > TT[t]) ? 1.0f : 0.0f;
            o += z * dd[t];
        }
        // jnp.sign: -1 / 0 / +1
        const float s = (xi > 0.0f) ? 1.0f : ((xi < 0.0f) ? -1.0f : 0.0f);
        r[i] = o * s;
    }

    ((float4*)out)[idx] = make_float4(r[0], r[1], r[2], r[3]);
}

extern "C" void kernel_launch(void* const* d_in, const int* in_sizes, int n_in,
                              void* d_out, int out_size, void* d_ws, size_t ws_size,
                              hipStream_t stream) {
    const float* x = (const float*)d_in[0];
    const float* h = (const float*)d_in[1];
    const float* d = (const float*)d_in[2];
    const float* T = (const float*)d_in[3];
    float* out = (float*)d_out;

    const int n = in_sizes[0];          // 134217728, divisible by 4
    const int n4 = n / 4;               // 33554432
    const int block = 256;
    const int grid = (n4 + block - 1) / block;  // 131072

    invert4_kernel<<<grid, block, 0, stream>>>(x, h, d, T, out, n4);
}